// Round 6
// baseline (162.925 us; speedup 1.0000x reference)
//
#include <hip/hip_runtime.h>
#include <math.h>

#define N_SEQ 2048
#define DM    512
#define NTOK  4096
#define NH    8
#define HD    64
#define NSLOT 18

typedef __attribute__((ext_vector_type(8))) short short8;
typedef __attribute__((ext_vector_type(4))) short short4_t;
typedef __attribute__((ext_vector_type(4))) float f32x4;

__device__ inline short f2bf(float x) {
    union { float f; unsigned u; } v; v.f = x;
    unsigned r = v.u + 0x7fff + ((v.u >> 16) & 1);
    return (short)(r >> 16);
}
__device__ inline float bf2f(short s) {
    union { unsigned u; float f; } v; v.u = ((unsigned)(unsigned short)s) << 16;
    return v.f;
}
__device__ inline unsigned pkbf(float a, float b) {
    return ((unsigned)(unsigned short)f2bf(b) << 16) | (unsigned)(unsigned short)f2bf(a);
}
__device__ inline float ftanh(float x) {
    float e = __expf(2.f * x);
    return 1.f - 2.f / (e + 1.f);
}

__device__ inline f32x4 mfma16(short8 a, short8 b, f32x4 c) {
    return __builtin_amdgcn_mfma_f32_16x16x32_bf16(a, b, c, 0, 0, 0);
}

__device__ __forceinline__ void async_cp16(const short* g, short* l) {
    __builtin_amdgcn_global_load_lds(
        (const __attribute__((address_space(1))) void*)g,
        (__attribute__((address_space(3))) void*)l, 16, 0, 0);
}

// ---------------- fused: LN(x)->bf16 + lg zero-init  |  weight cvt fp32->bf16 ----
__global__ __launch_bounds__(256) void k_lncvt(
    const float* __restrict__ x, const float* __restrict__ g,
    const float* __restrict__ b, short* __restrict__ y, float* __restrict__ lg,
    const float* __restrict__ Wq, const float* __restrict__ Wk,
    const float* __restrict__ Wv, const float* __restrict__ Tw1,
    const float* __restrict__ Wo,
    short* __restrict__ wcat, short* __restrict__ wo) {
    int blk = blockIdx.x, t = threadIdx.x;
    if (blk < 2048) {
        int sub = t >> 7, tt = t & 127;
        int tk = blk * 2 + sub;
        if (tt == 0) lg[tk] = 0.f;
        float4 xv = ((const float4*)(x + (size_t)tk * DM))[tt];
        float s = xv.x + xv.y + xv.z + xv.w;
        float q = xv.x*xv.x + xv.y*xv.y + xv.z*xv.z + xv.w*xv.w;
        for (int o = 32; o; o >>= 1) { s += __shfl_down(s, o); q += __shfl_down(q, o); }
        __shared__ float ls[4], lq[4];
        if ((t & 63) == 0) { ls[t >> 6] = s; lq[t >> 6] = q; }
        __syncthreads();
        s = ls[sub * 2] + ls[sub * 2 + 1];
        q = lq[sub * 2] + lq[sub * 2 + 1];
        float mu = s * (1.f / DM);
        float var = q * (1.f / DM) - mu * mu;
        float rs = rsqrtf(var + 1e-5f);
        float4 gv = ((const float4*)g)[tt], bv = ((const float4*)b)[tt];
        short4_t o;
        o[0] = f2bf((xv.x - mu) * rs * gv.x + bv.x);
        o[1] = f2bf((xv.y - mu) * rs * gv.y + bv.y);
        o[2] = f2bf((xv.z - mu) * rs * gv.z + bv.z);
        o[3] = f2bf((xv.w - mu) * rs * gv.w + bv.w);
        *(short4_t*)&y[(size_t)tk * DM + tt * 4] = o;
    } else {
        int id = (blk - 2048) * 256 + t;
        if (id < 262144) {
            int z = id >> 16; int off = id & 65535;
            const float* s = (z == 0) ? Wq : (z == 1) ? Wk : (z == 2) ? Wv : Tw1;
            float4 v = ((const float4*)s)[off];
            short4_t o = {f2bf(v.x), f2bf(v.y), f2bf(v.z), f2bf(v.w)};
            *(short4_t*)(wcat + (size_t)z * 262144 + (size_t)off * 4) = o;
        } else {
            int off = id - 262144;
            float4 v = ((const float4*)Wo)[off];
            short4_t o = {f2bf(v.x), f2bf(v.y), f2bf(v.z), f2bf(v.w)};
            *(short4_t*)(wo + (size_t)off * 4) = o;
        }
    }
}

// ---------------- bf16 MFMA NT-GEMM (QKV + T-logit fused) ----------------
// z==2 (V): writes TRANSPOSED vtb [b][h][d][n] directly (4 consecutive n per
// acc reg -> aligned 8B stores). No separate V-transpose kernel.
__global__ __launch_bounds__(256) void k_gemmqkvt(
    const short* __restrict__ A, const short* __restrict__ W,
    const float* __restrict__ Tb1, const float* __restrict__ Tw2,
    short* __restrict__ qb, short* __restrict__ kb, short* __restrict__ vtb,
    float* __restrict__ lg) {
    __shared__ short As[128 * 32];
    __shared__ short Bs[128 * 32];
    int t = threadIdx.x;
    int lane = t & 63, w = t >> 6;
    int wy = w >> 1, wx = w & 1;
    int ln = lane & 15, q4 = lane >> 4;
    int c0 = blockIdx.x * 128, m0 = blockIdx.y * 128;
    int sr = t >> 2, sc = (t & 3) << 3;
    f32x4 acc[4][4];
    f32x4 zero = {0.f, 0.f, 0.f, 0.f};
    #pragma unroll
    for (int i = 0; i < 4; i++)
        #pragma unroll
        for (int j = 0; j < 4; j++) acc[i][j] = zero;
    for (int k0 = 0; k0 < DM; k0 += 32) {
        __syncthreads();
        async_cp16(&A[(size_t)(m0 + sr) * DM + k0 + sc],      &As[sr * 32 + sc]);
        async_cp16(&A[(size_t)(m0 + 64 + sr) * DM + k0 + sc], &As[(64 + sr) * 32 + sc]);
        async_cp16(&W[(size_t)(c0 + sr) * DM + k0 + sc],      &Bs[sr * 32 + sc]);
        async_cp16(&W[(size_t)(c0 + 64 + sr) * DM + k0 + sc], &Bs[(64 + sr) * 32 + sc]);
        __syncthreads();
        short8 af[4], bfr[4];
        #pragma unroll
        for (int i = 0; i < 4; i++)
            af[i] = *(short8*)&As[(wy * 64 + i * 16 + ln) * 32 + q4 * 8];
        #pragma unroll
        for (int j = 0; j < 4; j++)
            bfr[j] = *(short8*)&Bs[(wx * 64 + j * 16 + ln) * 32 + q4 * 8];
        #pragma unroll
        for (int i = 0; i < 4; i++)
            #pragma unroll
            for (int j = 0; j < 4; j++)
                acc[i][j] = mfma16(af[i], bfr[j], acc[i][j]);
    }
    int z = c0 >> 9;
    if (z < 2) {
        short* dst = (z == 0) ? qb : kb;
        float sc2 = (z == 0) ? 0.125f : 1.0f;
        #pragma unroll
        for (int i = 0; i < 4; i++)
            #pragma unroll
            for (int j = 0; j < 4; j++)
                #pragma unroll
                for (int r = 0; r < 4; r++) {
                    int row = m0 + wy * 64 + i * 16 + q4 * 4 + r;
                    int col = c0 + wx * 64 + j * 16 + ln;
                    int nin = col & 511;
                    int h = nin >> 6, d = nin & 63;
                    int bi = row >> 11, n = row & (N_SEQ - 1);
                    dst[(((size_t)bi * NH + h) * N_SEQ + n) * HD + d] =
                        f2bf(acc[i][j][r] * sc2);
                }
    } else if (z == 2) {
        // V transposed: vtb[((bi*NH+h)*HD+d)*N_SEQ + n], 4 consecutive n per reg
        #pragma unroll
        for (int i = 0; i < 4; i++) {
            int row0 = m0 + wy * 64 + i * 16 + q4 * 4;
            int bi = row0 >> 11, n0 = row0 & (N_SEQ - 1);
            #pragma unroll
            for (int j = 0; j < 4; j++) {
                int nin = (c0 + wx * 64 + j * 16 + ln) & 511;
                int h = nin >> 6, d = nin & 63;
                short4_t o = {f2bf(acc[i][j][0]), f2bf(acc[i][j][1]),
                              f2bf(acc[i][j][2]), f2bf(acc[i][j][3])};
                *(short4_t*)&vtb[(((size_t)bi * NH + h) * HD + d) * N_SEQ + n0] = o;
            }
        }
    } else {
        #pragma unroll
        for (int i = 0; i < 4; i++) {
            #pragma unroll
            for (int r = 0; r < 4; r++) {
                float s = 0.f;
                #pragma unroll
                for (int j = 0; j < 4; j++) {
                    int tc = (c0 & 511) + wx * 64 + j * 16 + ln;
                    s += ftanh(acc[i][j][r] + Tb1[tc]) * Tw2[tc];
                }
                s += __shfl_xor(s, 1);
                s += __shfl_xor(s, 2);
                s += __shfl_xor(s, 4);
                s += __shfl_xor(s, 8);
                if (ln == 0) {
                    int row = m0 + wy * 64 + i * 16 + q4 * 4 + r;
                    atomicAdd(&lg[row], s);
                }
            }
        }
    }
}

// ---------------- proj GEMM 128x64 tiles: proj = A @ Wo^T ----------------
__global__ __launch_bounds__(256) void k_gemmp(
    const short* __restrict__ A, const short* __restrict__ W,
    float* __restrict__ proj) {
    __shared__ short As[128 * 32];
    __shared__ short Bs[64 * 32];
    int t = threadIdx.x;
    int lane = t & 63, w = t >> 6;
    int wy = w >> 1, wx = w & 1;
    int ln = lane & 15, q4 = lane >> 4;
    int c0 = blockIdx.x * 64, m0 = blockIdx.y * 128;
    int sr = t >> 2, sc = (t & 3) << 3;
    int br = t >> 2, bc = (t & 3) << 3;
    f32x4 acc[4][2];
    f32x4 zero = {0.f, 0.f, 0.f, 0.f};
    #pragma unroll
    for (int i = 0; i < 4; i++) { acc[i][0] = zero; acc[i][1] = zero; }
    for (int k0 = 0; k0 < DM; k0 += 32) {
        __syncthreads();
        async_cp16(&A[(size_t)(m0 + sr) * DM + k0 + sc],      &As[sr * 32 + sc]);
        async_cp16(&A[(size_t)(m0 + 64 + sr) * DM + k0 + sc], &As[(64 + sr) * 32 + sc]);
        if (br < 64)
            async_cp16(&W[(size_t)(c0 + br) * DM + k0 + bc], &Bs[br * 32 + bc]);
        __syncthreads();
        short8 af[4], bfr[2];
        #pragma unroll
        for (int i = 0; i < 4; i++)
            af[i] = *(short8*)&As[(wy * 64 + i * 16 + ln) * 32 + q4 * 8];
        #pragma unroll
        for (int j = 0; j < 2; j++)
            bfr[j] = *(short8*)&Bs[(wx * 32 + j * 16 + ln) * 32 + q4 * 8];
        #pragma unroll
        for (int i = 0; i < 4; i++)
            #pragma unroll
            for (int j = 0; j < 2; j++)
                acc[i][j] = mfma16(af[i], bfr[j], acc[i][j]);
    }
    #pragma unroll
    for (int i = 0; i < 4; i++)
        #pragma unroll
        for (int j = 0; j < 2; j++)
            #pragma unroll
            for (int r = 0; r < 4; r++) {
                int row = m0 + wy * 64 + i * 16 + q4 * 4 + r;
                int col = c0 + wx * 32 + j * 16 + ln;
                proj[(size_t)row * DM + col] = acc[i][j][r];
            }
}

// ---------------- split-K MFMA flash attention, 128-key tiles, reg-prefetch ----
__global__ __launch_bounds__(256) void k_attn(const short* __restrict__ qb,
                                              const short* __restrict__ kb,
                                              const short* __restrict__ vtb,
                                              short* __restrict__ P_O,
                                              float* __restrict__ P_ml) {
    __shared__ short Ks[128 * 72];      // [key][d] pad72
    __shared__ short Vt[64 * 136];      // [d][key] pad136
    __shared__ short Pa[4][16 * 136];   // per-wave [qrow][key] pad136
    int t = threadIdx.x;
    int lane = t & 63, w = t >> 6;
    int ln = lane & 15, q4 = lane >> 4;
    int slot = blockIdx.x, qt = blockIdx.y, bi = blockIdx.z;
    int q0 = qt * 64;
    int h, c;
    if (slot < 4)        { h = 0; c = slot; }
    else if (slot < 8)   { h = 1; c = slot - 4; }
    else if (slot == 8)  { h = 2; c = 0; }
    else if (slot == 9)  { h = 3; c = 0; }
    else if (slot < 12)  { h = 4; c = slot - 10; }
    else if (slot == 12) { h = 5; c = 0; }
    else if (slot < 15)  { h = 6; c = slot - 13; }
    else                 { h = 7; c = slot - 15; }
    int kind = (h < 2) ? 0 : (h < 5) ? 1 : 2;
    int wnd = (h == 2 || h >= 5) ? 64 : (h == 3) ? 128 : (h == 4) ? 256 : 0;
    int dsh = (h == 5) ? 1 : (h == 6) ? 2 : (h == 7) ? 3 : 0;
    int dmask = (1 << dsh) - 1;
    int wmax = (kind == 0) ? 0 : (wnd << dsh);
    int tLoU, tHiU, CS;
    if (kind == 0) { tLoU = 0; tHiU = 15; CS = 4; }
    else { tLoU = (q0 - wmax) >> 7; tHiU = (q0 + 63 + wmax) >> 7; CS = 3; }
    int ktLo = tLoU + c * CS;
    int ktHi = ktLo + CS - 1;
    if (ktHi > tHiU) ktHi = tHiU;
    if (ktHi > 15) ktHi = 15;
    if (ktLo < 0) ktLo = 0;
    int p4 = (bi * 32 + qt) * NSLOT + slot;
    float* ml = P_ml + (size_t)p4 * 128;
    if (ktLo > ktHi) {
        if (t < 64) { ml[t] = -1e30f; ml[64 + t] = 0.f; }
        return;
    }
    const size_t base = ((size_t)bi * NH + h) * N_SEQ * HD;
    const short* Q = qb + base;
    const short* K = kb + base;
    const short* Vg = vtb + base;   // [d][n]
    short8 qa[2];
    {
        const short* qrow = Q + (size_t)(q0 + w * 16 + ln) * HD + q4 * 8;
        qa[0] = *(const short8*)qrow;
        qa[1] = *(const short8*)(qrow + 32);
    }
    int qi = q0 + w * 16 + ln;
    float m_i = -1e30f, l_i = 0.f;
    f32x4 OT[4];
    f32x4 zero = {0.f, 0.f, 0.f, 0.f};
    #pragma unroll
    for (int d = 0; d < 4; d++) OT[d] = zero;
    short* Paw = Pa[w];
    // staging register prefetch: per-thread 4 K rows (short8) + 4 Vt chunks
    int skr = t >> 1, skc = (t & 1) << 3;   // id base for K: 2 thr/row? no: see loop
    (void)skr; (void)skc;
    short8 kreg[4], vreg[4];
    {
        int k0 = ktLo << 7;
        #pragma unroll
        for (int i2 = 0; i2 < 4; i2++) {
            int id = t + 256 * i2;
            int kr = id >> 3, cc = id & 7;
            kreg[i2] = *(const short8*)&K[(size_t)(k0 + kr) * HD + cc * 8];
            int dr = id >> 4, kc = id & 15;
            vreg[i2] = *(const short8*)&Vg[(size_t)dr * N_SEQ + k0 + kc * 8];
        }
    }
    for (int kt = ktLo; kt <= ktHi; kt++) {
        int k0 = kt << 7;
        __syncthreads();
        #pragma unroll
        for (int i2 = 0; i2 < 4; i2++) {
            int id = t + 256 * i2;
            int kr = id >> 3, cc = id & 7;
            *(short8*)&Ks[kr * 72 + cc * 8] = kreg[i2];
            int dr = id >> 4, kc = id & 15;
            *(short8*)&Vt[dr * 136 + kc * 8] = vreg[i2];
        }
        __syncthreads();
        if (kt < ktHi) {    // prefetch next tile while computing this one
            int kn = (kt + 1) << 7;
            #pragma unroll
            for (int i2 = 0; i2 < 4; i2++) {
                int id = t + 256 * i2;
                int kr = id >> 3, cc = id & 7;
                kreg[i2] = *(const short8*)&K[(size_t)(kn + kr) * HD + cc * 8];
                int dr = id >> 4, kc = id & 15;
                vreg[i2] = *(const short8*)&Vg[(size_t)dr * N_SEQ + kn + kc * 8];
            }
        }
        // S^T = K·Q^T over 128 keys
        f32x4 ST[8];
        #pragma unroll
        for (int nt = 0; nt < 8; nt++) ST[nt] = zero;
        #pragma unroll
        for (int nt = 0; nt < 8; nt++) {
            #pragma unroll
            for (int ks = 0; ks < 2; ks++) {
                short8 af = *(short8*)&Ks[(nt * 16 + ln) * 72 + ks * 32 + q4 * 8];
                ST[nt] = mfma16(af, qa[ks], ST[nt]);
            }
        }
        if (kind != 0) {
            #pragma unroll
            for (int nt = 0; nt < 8; nt++)
                #pragma unroll
                for (int r = 0; r < 4; r++) {
                    int key = k0 + nt * 16 + q4 * 4 + r;
                    int dlt = qi - key; dlt = (dlt < 0) ? -dlt : dlt;
                    int valid;
                    if (kind == 1) valid = (dlt <= wnd);
                    else valid = ((dlt & dmask) == 0) && ((dlt >> dsh) <= wnd);
                    if (!valid) ST[nt][r] = -1e30f;
                }
        }
        float rm = -1e30f;
        #pragma unroll
        for (int nt = 0; nt < 8; nt++) {
            float a = fmaxf(ST[nt][0], ST[nt][1]);
            float b = fmaxf(ST[nt][2], ST[nt][3]);
            rm = fmaxf(rm, fmaxf(a, b));
        }
        rm = fmaxf(rm, __shfl_xor(rm, 16));
        rm = fmaxf(rm, __shfl_xor(rm, 32));
        float mn = fmaxf(m_i, rm);
        float sc = __expf(m_i - mn);
        float rs = 0.f;
        #pragma unroll
        for (int nt = 0; nt < 8; nt++) {
            float p0 = __expf(ST[nt][0] - mn);
            float p1 = __expf(ST[nt][1] - mn);
            float p2 = __expf(ST[nt][2] - mn);
            float p3 = __expf(ST[nt][3] - mn);
            rs += (p0 + p1) + (p2 + p3);
            *(unsigned*)&Paw[ln * 136 + nt * 16 + q4 * 4]     = pkbf(p0, p1);
            *(unsigned*)&Paw[ln * 136 + nt * 16 + q4 * 4 + 2] = pkbf(p2, p3);
        }
        rs += __shfl_xor(rs, 16);
        rs += __shfl_xor(rs, 32);
        l_i = l_i * sc + rs;
        m_i = mn;
        #pragma unroll
        for (int d = 0; d < 4; d++) OT[d] *= sc;
        short8 pb[4];
        #pragma unroll
        for (int ks = 0; ks < 4; ks++)
            pb[ks] = *(short8*)&Paw[ln * 136 + ks * 32 + q4 * 8];
        #pragma unroll
        for (int dt = 0; dt < 4; dt++) {
            #pragma unroll
            for (int ks = 0; ks < 4; ks++) {
                short8 a = *(short8*)&Vt[(dt * 16 + ln) * 136 + ks * 32 + q4 * 8];
                OT[dt] = mfma16(a, pb[ks], OT[dt]);
            }
        }
    }
    if (q4 == 0) { ml[w * 16 + ln] = m_i; ml[64 + w * 16 + ln] = l_i; }
    #pragma unroll
    for (int dt = 0; dt < 4; dt++) {
        *(unsigned*)&Paw[ln * 136 + dt * 16 + q4 * 4]     = pkbf(OT[dt][0], OT[dt][1]);
        *(unsigned*)&Paw[ln * 136 + dt * 16 + q4 * 4 + 2] = pkbf(OT[dt][2], OT[dt][3]);
    }
    short8 o0 = *(short8*)&Paw[ln * 136 + q4 * 16];
    short8 o1 = *(short8*)&Paw[ln * 136 + q4 * 16 + 8];
    short* Op = P_O + (size_t)p4 * 4096;
    *(short8*)&Op[(w * 16 + ln) * 64 + q4 * 16] = o0;
    *(short8*)&Op[(w * 16 + ln) * 64 + q4 * 16 + 8] = o1;
}

// ---------------- combine partials -> obuf  |  gate softmax ----------------
// blocks 0..511: combine (h = blk&7, qt = (blk>>3)&31, bi = blk>>8).
// blocks 512,513: gate softmax for batch blk-512.
__global__ __launch_bounds__(256) void k_combgate(const short* __restrict__ P_O,
                                                  const float* __restrict__ P_ml,
                                                  short* __restrict__ ob,
                                                  const float* __restrict__ lg,
                                                  float* __restrict__ gate) {
    int blk = blockIdx.x, t = threadIdx.x;
    if (blk < 512) {
        const int hbase[8] = {0, 4, 8, 9, 10, 12, 13, 15};
        const int hcnt[8]  = {4, 4, 1, 1, 2, 1, 2, 3};
        int h = blk & 7, qt = (blk >> 3) & 31, bi = blk >> 8;
        int row = t >> 2, c0 = (t & 3) * 16;
        int pb = (bi * 32 + qt) * NSLOT + hbase[h];
        int cnt = hcnt[h];
        float m = -1e30f;
        for (int s = 0; s < cnt; s++)
            m = fmaxf(m, P_ml[(size_t)(pb + s) * 128 + row]);
        float l = 0.f;
        float acc[16];
        #pragma unroll
        for (int j = 0; j < 16; j++) acc[j] = 0.f;
        for (int s = 0; s < cnt; s++) {
            float ms = P_ml[(size_t)(pb + s) * 128 + row];
            float ls = P_ml[(size_t)(pb + s) * 128 + 64 + row];
            if (ls > 0.f) {
                float sc = __expf(ms - m);
                l += ls * sc;
                const short* Op = P_O + (size_t)(pb + s) * 4096 + row * 64 + c0;
                short8 v0 = *(const short8*)Op;
                short8 v1 = *(const short8*)(Op + 8);
                #pragma unroll
                for (int j = 0; j < 8; j++) acc[j]     += bf2f(v0[j]) * sc;
                #pragma unroll
                for (int j = 0; j < 8; j++) acc[8 + j] += bf2f(v1[j]) * sc;
            }
        }
        float inv = 1.f / l;
        int n = qt * 64 + row;
        short8 o0, o1;
        #pragma unroll
        for (int j = 0; j < 8; j++) o0[j] = f2bf(acc[j] * inv);
        #pragma unroll
        for (int j = 0; j < 8; j++) o1[j] = f2bf(acc[8 + j] * inv);
        short* dst = ob + ((size_t)bi * N_SEQ + n) * DM + h * 64 + c0;
        *(short8*)dst = o0;
        *(short8*)(dst + 8) = o1;
    } else {
        __shared__ float rg[8];
        int b = blk - 512;
        float v[8];
        {
            float4 a0 = *(const float4*)&lg[b * N_SEQ + t * 8];
            float4 a1 = *(const float4*)&lg[b * N_SEQ + t * 8 + 4];
            v[0] = a0.x; v[1] = a0.y; v[2] = a0.z; v[3] = a0.w;
            v[4] = a1.x; v[5] = a1.y; v[6] = a1.z; v[7] = a1.w;
        }
        float m = v[0];
        #pragma unroll
        for (int j = 1; j < 8; j++) m = fmaxf(m, v[j]);
        for (int o = 32; o; o >>= 1) m = fmaxf(m, __shfl_down(m, o));
        if ((t & 63) == 0) rg[t >> 6] = m;
        __syncthreads();
        m = fmaxf(fmaxf(rg[0], rg[1]), fmaxf(rg[2], rg[3]));
        float e[8], s = 0.f;
        #pragma unroll
        for (int j = 0; j < 8; j++) { e[j] = __expf(v[j] - m); s += e[j]; }
        for (int o = 32; o; o >>= 1) s += __shfl_down(s, o);
        if ((t & 63) == 0) rg[4 + (t >> 6)] = s;
        __syncthreads();
        s = (rg[4] + rg[5]) + (rg[6] + rg[7]);
        float inv = 1.f / s;
        float4 o0 = {e[0] * inv, e[1] * inv, e[2] * inv, e[3] * inv};
        float4 o1 = {e[4] * inv, e[5] * inv, e[6] * inv, e[7] * inv};
        *(float4*)&gate[b * N_SEQ + t * 8] = o0;
        *(float4*)&gate[b * N_SEQ + t * 8 + 4] = o1;
    }
}

// ---------------- final: y = proj*gate + x0 ; LN_out ----------------
__global__ __launch_bounds__(128) void k_final(const float* __restrict__ proj,
                                               const float* __restrict__ gate,
                                               const float* __restrict__ x0,
                                               const float* __restrict__ g,
                                               const float* __restrict__ b,
                                               float* __restrict__ out) {
    int tk = blockIdx.x, t = threadIdx.x;
    float gt = gate[tk];
    float4 pv = ((const float4*)(proj + (size_t)tk * DM))[t];
    float4 xv = ((const float4*)(x0 + (size_t)tk * DM))[t];
    float4 y;
    y.x = pv.x * gt + xv.x;
    y.y = pv.y * gt + xv.y;
    y.z = pv.z * gt + xv.z;
    y.w = pv.w * gt + xv.w;
    float s = y.x + y.y + y.z + y.w;
    float q = y.x*y.x + y.y*y.y + y.z*y.z + y.w*y.w;
    for (int o = 32; o; o >>= 1) { s += __shfl_down(s, o); q += __shfl_down(q, o); }
    __shared__ float ls[2], lq[2];
    if ((t & 63) == 0) { ls[t >> 6] = s; lq[t >> 6] = q; }
    __syncthreads();
    s = ls[0] + ls[1]; q = lq[0] + lq[1];
    float mu = s * (1.f / DM);
    float var = q * (1.f / DM) - mu * mu;
    float rs = rsqrtf(var + 1e-5f);
    float4 gv = ((const float4*)g)[t], bv = ((const float4*)b)[t];
    float4 o;
    o.x = (y.x - mu) * rs * gv.x + bv.x;
    o.y = (y.y - mu) * rs * gv.y + bv.y;
    o.z = (y.z - mu) * rs * gv.z + bv.z;
    o.w = (y.w - mu) * rs * gv.w + bv.w;
    ((float4*)(out + (size_t)tk * DM))[t] = o;
}

extern "C" void kernel_launch(void* const* d_in, const int* in_sizes, int n_in,
                              void* d_out, int out_size, void* d_ws, size_t ws_size,
                              hipStream_t stream) {
    (void)in_sizes; (void)n_in; (void)out_size; (void)ws_size;
    const float* x    = (const float*)d_in[0];
    const float* Wq   = (const float*)d_in[1];
    const float* Wk   = (const float*)d_in[2];
    const float* Wv   = (const float*)d_in[3];
    const float* Wo   = (const float*)d_in[4];
    const float* Tw1  = (const float*)d_in[5];
    const float* Tb1  = (const float*)d_in[6];
    const float* Tw2  = (const float*)d_in[7];
    const float* ling = (const float*)d_in[9];
    const float* linb = (const float*)d_in[10];
    const float* logg = (const float*)d_in[11];
    const float* logb = (const float*)d_in[12];
    float* out = (float*)d_out;

    const size_t SZ = (size_t)NTOK * DM;
    const int NPART = 2 * 32 * NSLOT;  // 1152 partial tiles
    char* p = (char*)d_ws;
    short* xn   = (short*)p; p += SZ * 2;
    short* wcat = (short*)p; p += (size_t)2048 * DM * 2;
    short* wo   = (short*)p; p += (size_t)DM * DM * 2;
    short* qb   = (short*)p; p += SZ * 2;
    short* kb   = (short*)p; p += SZ * 2;
    short* vtb  = (short*)p; p += SZ * 2;
    short* obuf = (short*)p; p += SZ * 2;
    float* lg   = (float*)p; p += (size_t)NTOK * 4;
    float* gate = (float*)p; p += (size_t)NTOK * 4;
    float* P_ml = (float*)p; p += (size_t)NPART * 128 * 4;
    // proj (8 MB fp32) aliases P_O (9.4 MB bf16): P_O dead after k_combgate;
    // proj written only by the later Wo GEMM.
    float* proj = (float*)p;
    short* P_O  = (short*)p; p += (size_t)NPART * 4096 * 2;

    k_lncvt<<<3328, 256, 0, stream>>>(x, ling, linb, xn, lg,
                                      Wq, Wk, Wv, Tw1, Wo, wcat, wo);
    k_gemmqkvt<<<dim3(16, 32), 256, 0, stream>>>(xn, wcat, Tb1, Tw2,
                                                 qb, kb, vtb, lg);
    k_attn<<<dim3(NSLOT, 32, 2), 256, 0, stream>>>(qb, kb, vtb, P_O, P_ml);
    k_combgate<<<514, 256, 0, stream>>>(P_O, P_ml, obuf, lg, gate);
    k_gemmp<<<dim3(8, 32), 256, 0, stream>>>(obuf, wo, proj);
    k_final<<<NTOK, 128, 0, stream>>>(proj, gate, x, logg, logb, out);
}